// Round 5
// baseline (566.438 us; speedup 1.0000x reference)
//
#include <hip/hip_runtime.h>
#include <cstdint>
#include <cstddef>

#define BB 32
#define NN 1024
#define CIN 128
#define FF 64
#define NOUT 10
#define CAP 128
#define EPSV 1e-5f

// non-temporal float4 load: stream-once data (A, x, Xin) must not evict gather-hot rows.
typedef float vf4 __attribute__((ext_vector_type(4)));
__device__ __forceinline__ float4 ldnt(const float4* p) {
    vf4 v = __builtin_nontemporal_load((const vf4*)p);
    return make_float4(v.x, v.y, v.z, v.w);
}

// ---------------- fused front: [0,8192) CSR, [8192,10240) x@W0 gemm, [10240] seed ----
// R5: seed block also zeroes the 3 per-graph arrival-counter arrays (ws is poisoned).
__global__ __launch_bounds__(256) void k_front(const float* __restrict__ A,
                                               const float* __restrict__ x,
                                               const float* __restrict__ W0,
                                               const int* __restrict__ Nn,
                                               const float* __restrict__ b2f,
                                               float* __restrict__ gmax,
                                               unsigned short* __restrict__ adj,
                                               int* __restrict__ cnt,
                                               float* __restrict__ c1,
                                               float* __restrict__ c2,
                                               float* __restrict__ T,
                                               int* __restrict__ ctrs) {
    __shared__ __align__(16) float Wl[64 * 64];    // 16 KB
    int tid = threadIdx.x;
    int wave = tid >> 6, lane = tid & 63;
    if (blockIdx.x >= 10240) {
        for (int i = tid; i < BB * 64; i += 256)
            gmax[i] = fmaxf(b2f[i & 63], 0.f);     // exact relu(b2) seed (dead rows)
        if (tid < 96) ctrs[tid] = 0;               // 3 x 32 arrival counters
        return;
    }
    if (blockIdx.x >= 8192) {
        int gid = blockIdx.x - 8192;        // gid%8 == b%8: XCD matches spmm
        int b = gid & 31;
        int cch = gid >> 5;
        if (cch * 16 >= Nn[b]) return;
        int row0 = (b << 10) + cch * 16;
        int rsub = lane >> 4, f0 = (lane & 15) * 4;
        int r = row0 + wave * 4 + rsub;
        const float4* xr = (const float4*)(x + (size_t)r * CIN);
        float4 acc = {0.f, 0.f, 0.f, 0.f};
#pragma unroll
        for (int kc = 0; kc < 2; ++kc) {
            if (kc) __syncthreads();
            for (int t = tid; t < 64 * 16; t += 256)
                ((float4*)Wl)[t] = ((const float4*)W0)[kc * 1024 + t];
            __syncthreads();
#pragma unroll 4
            for (int k4 = 0; k4 < 16; ++k4) {
                float4 xv = ldnt(xr + kc * 16 + k4);
                float4 w0 = *(const float4*)&Wl[(k4 * 4 + 0) * 64 + f0];
                float4 w1 = *(const float4*)&Wl[(k4 * 4 + 1) * 64 + f0];
                float4 w2 = *(const float4*)&Wl[(k4 * 4 + 2) * 64 + f0];
                float4 w3 = *(const float4*)&Wl[(k4 * 4 + 3) * 64 + f0];
                acc.x += xv.x * w0.x; acc.y += xv.x * w0.y; acc.z += xv.x * w0.z; acc.w += xv.x * w0.w;
                acc.x += xv.y * w1.x; acc.y += xv.y * w1.y; acc.z += xv.y * w1.z; acc.w += xv.y * w1.w;
                acc.x += xv.z * w2.x; acc.y += xv.z * w2.y; acc.z += xv.z * w2.z; acc.w += xv.z * w2.w;
                acc.x += xv.w * w3.x; acc.y += xv.w * w3.y; acc.z += xv.w * w3.z; acc.w += xv.w * w3.w;
            }
        }
        *(float4*)&T[(size_t)r * 64 + f0] = acc;
    } else {
        int r = blockIdx.x * 4 + wave;
        int b = r >> 10;
        int Nb = Nn[b];
        int rl = r & 1023;
        if (rl >= Nb) {
            if (lane == 0) {
                cnt[r] = 0;
                float D = 1.0f / sqrtf(1.0f + EPSV);
                c1[r] = D;
                c2[r] = D * D;
            }
            return;
        }
        unsigned short* adjs = ((unsigned short*)Wl) + wave * CAP;
        const float4* Arow = (const float4*)(A + (size_t)r * NN);
        int nch = (Nb + 255) >> 8;
        float4 z4 = {0.f, 0.f, 0.f, 0.f};
        float4 v0 = ldnt(Arow + lane);
        float4 v1 = ldnt(Arow + 64 + lane);
        float4 v2 = (nch > 2) ? ldnt(Arow + 128 + lane) : z4;
        float4 v3 = (nch > 3) ? ldnt(Arow + 192 + lane) : z4;
        int c = 0;
        unsigned long long lt = (lane == 0) ? 0ULL : ((1ULL << lane) - 1ULL);
        float4 vv[4] = {v0, v1, v2, v3};
#pragma unroll
        for (int it = 0; it < 4; ++it) {
            float4 v = vv[it];
            int j0 = it * 256 + lane * 4;
            unsigned long long m0 = __ballot(v.x != 0.f);
            unsigned long long m1 = __ballot(v.y != 0.f);
            unsigned long long m2 = __ballot(v.z != 0.f);
            unsigned long long m3 = __ballot(v.w != 0.f);
            int before = __popcll(m0 & lt) + __popcll(m1 & lt) +
                         __popcll(m2 & lt) + __popcll(m3 & lt);
            int p = c + before;
            if (v.x != 0.f) { if (p < CAP) adjs[p] = (unsigned short)(j0 + 0); ++p; }
            if (v.y != 0.f) { if (p < CAP) adjs[p] = (unsigned short)(j0 + 1); ++p; }
            if (v.z != 0.f) { if (p < CAP) adjs[p] = (unsigned short)(j0 + 2); ++p; }
            if (v.w != 0.f) { if (p < CAP) adjs[p] = (unsigned short)(j0 + 3); ++p; }
            c += __popcll(m0) + __popcll(m1) + __popcll(m2) + __popcll(m3);
        }
        int cc = (c > CAP) ? CAP : c;
        uint32_t* dst = (uint32_t*)(adj + (size_t)r * CAP);
        if (lane * 2 < cc) dst[lane] = ((const uint32_t*)adjs)[lane];
        if (lane == 0) {
            cnt[r] = cc;
            float D = 1.0f / sqrtf((float)c + 1.0f + EPSV);
            c1[r] = D;
            c2[r] = D * D;
        }
    }
}

// ---------------- fused mid: [0,8192) = deg, [8192,10240) = gemm64 (scaled) --------------
// byte-identical to R3 (proven).
__global__ __launch_bounds__(256) void k_mid(const unsigned short* __restrict__ adj,
                                             const int* __restrict__ cnt,
                                             const float* __restrict__ nm,
                                             float* __restrict__ c1, float* __restrict__ c2,
                                             const float* __restrict__ Xin,
                                             const float* __restrict__ W,
                                             const float* __restrict__ y,
                                             float* __restrict__ T,
                                             const int* __restrict__ Nn) {
    __shared__ __align__(16) float Wl[64 * 64];    // 16 KB
    int tid = threadIdx.x;
    if (blockIdx.x >= 8192) {
        int gid = blockIdx.x - 8192;
        int b = gid & 31;
        int cch = gid >> 5;
        if (cch * 16 >= Nn[b]) return;
        int row0 = (b << 10) + cch * 16;
        for (int t = tid; t < 64 * 16; t += 256)
            ((float4*)Wl)[t] = ((const float4*)W)[t];
        __syncthreads();
        int wave = tid >> 6, lane = tid & 63;
        int rsub = lane >> 4, f0 = (lane & 15) * 4;
        int r = row0 + wave * 4 + rsub;
        float sc = tanhf(y[r]) * nm[r];
        const float4* xr = (const float4*)(Xin + (size_t)r * 64);
        float4 acc = {0.f, 0.f, 0.f, 0.f};
#pragma unroll 4
        for (int k4 = 0; k4 < 16; ++k4) {
            float4 xv = ldnt(xr + k4);
            float4 w0 = *(const float4*)&Wl[(k4 * 4 + 0) * 64 + f0];
            float4 w1 = *(const float4*)&Wl[(k4 * 4 + 1) * 64 + f0];
            float4 w2 = *(const float4*)&Wl[(k4 * 4 + 2) * 64 + f0];
            float4 w3 = *(const float4*)&Wl[(k4 * 4 + 3) * 64 + f0];
            acc.x += xv.x * w0.x; acc.y += xv.x * w0.y; acc.z += xv.x * w0.z; acc.w += xv.x * w0.w;
            acc.x += xv.y * w1.x; acc.y += xv.y * w1.y; acc.z += xv.y * w1.z; acc.w += xv.y * w1.w;
            acc.x += xv.z * w2.x; acc.y += xv.z * w2.y; acc.z += xv.z * w2.z; acc.w += xv.z * w2.w;
            acc.x += xv.w * w3.x; acc.y += xv.w * w3.y; acc.z += xv.w * w3.z; acc.w += xv.w * w3.w;
        }
        acc.x *= sc; acc.y *= sc; acc.z *= sc; acc.w *= sc;
        *(float4*)&T[(size_t)r * 64 + f0] = acc;
    } else {
        int wave = tid >> 6, lane = tid & 63;
        int r = blockIdx.x * 4 + wave;
        int b = r >> 10;
        if ((r & 1023) >= Nn[b]) return;
        float m = nm[r];
        if (m == 0.f) {
            if (lane == 0) c1[r] = 0.f;
            return;
        }
        const unsigned short* arow = adj + (size_t)r * CAP;
        const float* nmb = nm + (b << 10);
        int n = cnt[r];
        float s = 0.f;
        if (lane < n)      s  = nmb[arow[lane]];
        if (lane + 64 < n) s += nmb[arow[lane + 64]];
        for (int sh = 32; sh; sh >>= 1) s += __shfl_xor(s, sh, 64);
        if (lane == 0) {
            float D = 1.0f / sqrtf(m * s + 1.0f + EPSV);
            c1[r] = m * D;
            c2[r] = D * D;
        }
    }
}

// ---------------- SpMM (R3-proven body) + per-graph LAST-BLOCK tail (rank OR fc) --------
// Arrival: each live block, after all its global writes, does release-fence +
// atomicAdd(ctr[b]); the block seeing old==target-1 acquires and runs the tail:
//   rank tail: R4-verified u64-key stable ranking of all 1024 nodes -> nmOut, ncur.
//   fc tail:   gmax (seeded + atomicMax'ed) -> out[b], identical numerics to k_fc.
__global__ __launch_bounds__(256) void k_spmm(const unsigned short* __restrict__ adj,
                                              const int* __restrict__ cnt,
                                              const float* __restrict__ c1,
                                              const float* __restrict__ c2,
                                              const float* __restrict__ T,
                                              const float* __restrict__ bias,
                                              float* __restrict__ X,
                                              const float* __restrict__ p,
                                              float* __restrict__ y,
                                              float* __restrict__ gmax,
                                              const int* __restrict__ Nn,
                                              const float* __restrict__ maskSrc,
                                              const int* __restrict__ nsrc,
                                              float* __restrict__ nmOut,
                                              int* __restrict__ ncur,
                                              const float* __restrict__ Wfc,
                                              const float* __restrict__ bfc,
                                              float* __restrict__ outP,
                                              int* __restrict__ ctr) {
    __shared__ __align__(16) float c1s[NN];                    // 4 KB (reused by tails)
    __shared__ __align__(16) unsigned long long kv[NN];        // 8 KB (rank tail)
    __shared__ float red[4][64];
    __shared__ int islast;
    int b   = blockIdx.x & 31;            // graph
    int cch = blockIdx.x >> 5;            // chunk in [0,64)
    int Nb = Nn[b];
    if (cch * 16 >= Nb) return;           // dead chunk: not counted in arrival target
    int tid = threadIdx.x;
    int n4 = (Nb + 3) >> 2;
    if (tid < n4) ((float4*)c1s)[tid] = ((const float4*)(c1 + (b << 10)))[tid];
    __syncthreads();
    int wave = tid >> 6, lane = tid & 63;
    int r0 = (b << 10) + cch * 16 + wave * 4;
    const float* Tb = T + ((size_t)(b << 10) << 6);
    float bv = bias[lane];
    float pv = 0.f, ppinv = 0.f;
    if (p != nullptr) {
        pv = p[lane];
        float pp = pv * pv;
        for (int s = 32; s; s >>= 1) pp += __shfl_xor(pp, s, 64);
        ppinv = 1.0f / sqrtf(pp);
    }
    float vmax = 0.f;
#pragma unroll
    for (int rr = 0; rr < 4; ++rr) {
        int r = r0 + rr;
        int rl = r & 1023;
        if (rl >= Nb) break;
        if (c1s[rl] == 0.f) continue;     // pool-dropped (layers 2/3); layer-1 c1>0
        const unsigned short* arow = adj + (size_t)r * CAP;
        int n = cnt[r];
        float acc0 = 0.f, acc1 = 0.f, acc2 = 0.f, acc3 = 0.f;
        int t = 0;
        for (; t + 4 <= n; t += 4) {
            ushort4 j4 = *(const ushort4*)(arow + t);
            acc0 += c1s[j4.x] * Tb[((int)j4.x << 6) + lane];
            acc1 += c1s[j4.y] * Tb[((int)j4.y << 6) + lane];
            acc2 += c1s[j4.z] * Tb[((int)j4.z << 6) + lane];
            acc3 += c1s[j4.w] * Tb[((int)j4.w << 6) + lane];
        }
        for (; t < n; ++t) {
            int j = arow[t];
            acc0 += c1s[j] * Tb[(j << 6) + lane];
        }
        float acc = (acc0 + acc1) + (acc2 + acc3);
        float o = c1s[rl] * acc + c2[r] * T[((size_t)r << 6) + lane] + bv;
        o = fmaxf(o, 0.f);
        if (X != nullptr) X[((size_t)r << 6) + lane] = o;
        if (p != nullptr) {
            float a = o * pv;
            for (int s = 32; s; s >>= 1) a += __shfl_xor(a, s, 64);
            if (lane == 0) y[r] = a * ppinv;
        }
        vmax = fmaxf(vmax, o);
    }
    if (gmax != nullptr) {
        red[wave][lane] = vmax;
        __syncthreads();
        if (wave == 0) {
            float m = fmaxf(fmaxf(red[0][lane], red[1][lane]),
                            fmaxf(red[2][lane], red[3][lane]));
            atomicMax((int*)&gmax[(b << 6) + lane], __float_as_int(m));
        }
    }
    // ---- arrival: last live block of graph b runs the tail ----
    __syncthreads();                       // all waves' stores/atomics issued
    if (tid == 0) {
        __threadfence();                   // release: L2 writeback (cross-XCD, G16)
        int target = (Nb + 15) >> 4;
        int old = __hip_atomic_fetch_add(&ctr[b], 1, __ATOMIC_ACQ_REL,
                                         __HIP_MEMORY_SCOPE_AGENT);
        islast = (old == target - 1);
    }
    __syncthreads();
    if (!islast) return;
    __threadfence();                       // acquire: invalidate stale lines
    const float INF = __builtin_inff();
    if (nmOut != nullptr) {
        // ---- rank tail (R4-verified u64-key method), all 1024 nodes, one block ----
        float* yv = c1s;                   // c1s no longer needed
        {
            float4 v;
            if (tid * 4 < Nb) {
                v = ((const float4*)(y + (b << 10)))[tid];
                float4 m = ((const float4*)(maskSrc + (b << 10)))[tid];
                v.x = (m.x > 0.f) ? v.x : INF;
                v.y = (m.y > 0.f) ? v.y : INF;
                v.z = (m.z > 0.f) ? v.z : INF;
                v.w = (m.w > 0.f) ? v.w : INF;
            } else {
                v.x = INF; v.y = INF; v.z = INF; v.w = INF;
            }
            ((float4*)yv)[tid] = v;
        }
        int n = nsrc[b];
        const float RM = (float)(1.0 - 0.8);   // 0.2f, matches jax f32 semantics
        int nrem = (int)((float)n * RM);
        if (tid == 0) ncur[b] = n - nrem;
        __syncthreads();
#pragma unroll
        for (int t = 0; t < 4; ++t) {          // monotone order keys, idx tie-break
            int i = tid + (t << 8);
            unsigned int u = __float_as_uint(yv[i]);
            u ^= (unsigned int)((int)u >> 31) | 0x80000000u;
            kv[i] = ((unsigned long long)u << 10) | (unsigned int)i;
        }
        __syncthreads();
        unsigned long long k0 = kv[tid], k1 = kv[tid + 256],
                           k2 = kv[tid + 512], k3 = kv[tid + 768];
        int r0k = 0, r1k = 0, r2k = 0, r3k = 0;
        int nkc = (Nb + 1) >> 1;               // tail key (odd Nb) is INF: counts 0
#pragma unroll 4
        for (int c = 0; c < nkc; ++c) {
            ulonglong2 a = ((const ulonglong2*)kv)[c];
            r0k += (a.x < k0) + (a.y < k0);
            r1k += (a.x < k1) + (a.y < k1);
            r2k += (a.x < k2) + (a.y < k2);
            r3k += (a.x < k3) + (a.y < k3);
        }
        int rk[4] = {r0k, r1k, r2k, r3k};
#pragma unroll
        for (int t = 0; t < 4; ++t) {
            int i = tid + (t << 8);
            nmOut[(b << 10) + i] = (yv[i] < INF && rk[t] >= nrem) ? 1.f : 0.f;
        }
    } else if (outP != nullptr) {
        // ---- fc tail: identical numerics to the old k_fc (ascending k) ----
        float* gl = c1s;
        if (tid < 64)
            gl[tid] = __uint_as_float(__hip_atomic_load(
                (unsigned int*)&gmax[(b << 6) + tid],
                __ATOMIC_RELAXED, __HIP_MEMORY_SCOPE_AGENT));
        __syncthreads();
        if (tid < NOUT) {
            float acc = bfc[tid];
            for (int k = 0; k < 64; ++k) acc += gl[k] * Wfc[k * NOUT + tid];
            outP[b * NOUT + tid] = acc;
        }
    }
}

extern "C" void kernel_launch(void* const* d_in, const int* in_sizes, int n_in,
                              void* d_out, int out_size, void* d_ws, size_t ws_size,
                              hipStream_t stream) {
    const float* x    = (const float*)d_in[0];
    const float* A    = (const float*)d_in[1];
    const float* mask = (const float*)d_in[2];
    const int*   Nn   = (const int*)d_in[3];
    const float* W0   = (const float*)d_in[4];
    const float* b0   = (const float*)d_in[5];
    const float* W1   = (const float*)d_in[6];
    const float* b1   = (const float*)d_in[7];
    const float* W2   = (const float*)d_in[8];
    const float* b2   = (const float*)d_in[9];
    const float* p0   = (const float*)d_in[10];
    const float* p1   = (const float*)d_in[11];
    const float* Wfc  = (const float*)d_in[12];
    const float* bfc  = (const float*)d_in[13];
    float* out = (float*)d_out;

    char* ws = (char*)d_ws;
    size_t off = 0;
    auto alloc = [&](size_t bytes) -> void* {
        void* p = ws + off;
        off = (off + bytes + 255) & ~(size_t)255;
        return p;
    };
    unsigned short* adj = (unsigned short*)alloc((size_t)BB * NN * CAP * 2);
    int*   cnt  = (int*)  alloc((size_t)BB * NN * 4);
    float* X    = (float*)alloc((size_t)BB * NN * 64 * 4);
    float* T    = (float*)alloc((size_t)BB * NN * 64 * 4);
    float* c1   = (float*)alloc((size_t)BB * NN * 4);
    float* c2   = (float*)alloc((size_t)BB * NN * 4);
    float* y    = (float*)alloc((size_t)BB * NN * 4);
    float* nm0  = (float*)alloc((size_t)BB * NN * 4);
    float* nm1  = (float*)alloc((size_t)BB * NN * 4);
    int*   nc0  = (int*)  alloc((size_t)BB * 4);
    int*   nc1  = (int*)  alloc((size_t)BB * 4);
    float* gmax = (float*)alloc((size_t)BB * 64 * 4);
    int*   ctrs = (int*)  alloc(96 * 4);          // 3 arrival-counter arrays

    // 1) fused: CSR (8192) + x@W0 gemm (2048) + seed/ctr-zero (1 block)
    k_front<<<8192 + 2048 + 1, 256, 0, stream>>>(A, x, W0, Nn, b2, gmax,
                                                 adj, cnt, c1, c2, T, ctrs);
    // 2) layer-1 SpMM + score; last block per graph: pool-1 rank -> nm0, nc0
    k_spmm<<<2048, 256, 0, stream>>>(adj, cnt, c1, c2, T, b0, X, p0, y, nullptr, Nn,
                                     mask, Nn, nm0, nc0,
                                     nullptr, nullptr, nullptr, ctrs);
    // 3) layer 2: fused deg (first) + gemm64
    k_mid<<<8192 + 2048, 256, 0, stream>>>(adj, cnt, nm0, c1, c2, X, W1, y, T, Nn);
    // 4) layer-2 SpMM + score; last block per graph: pool-2 rank -> nm1, nc1
    k_spmm<<<2048, 256, 0, stream>>>(adj, cnt, c1, c2, T, b1, X, p1, y, nullptr, Nn,
                                     nm0, nc0, nm1, nc1,
                                     nullptr, nullptr, nullptr, ctrs + 32);
    // 5) layer 3: fused deg (first) + gemm64
    k_mid<<<8192 + 2048, 256, 0, stream>>>(adj, cnt, nm1, c1, c2, X, W2, y, T, Nn);
    // 6) layer-3 SpMM + fused gmax; last block per graph: fc -> out
    k_spmm<<<2048, 256, 0, stream>>>(adj, cnt, c1, c2, T, b2, nullptr, nullptr, nullptr,
                                     gmax, Nn,
                                     nullptr, nullptr, nullptr, nullptr,
                                     Wfc, bfc, out, ctrs + 64);
}

// Round 6
// 357.615 us; speedup vs baseline: 1.5839x; 1.5839x over previous
//
#include <hip/hip_runtime.h>
#include <cstdint>
#include <cstddef>

#define BB 32
#define NN 1024
#define CIN 128
#define FF 64
#define NOUT 10
#define CAP 128
#define EPSV 1e-5f

// non-temporal float4 load: stream-once data (A, x, Xin) must not evict gather-hot rows.
typedef float vf4 __attribute__((ext_vector_type(4)));
__device__ __forceinline__ float4 ldnt(const float4* p) {
    vf4 v = __builtin_nontemporal_load((const vf4*)p);
    return make_float4(v.x, v.y, v.z, v.w);
}

// ---------------- fused front: [0,8192) CSR, [8192,10240) x@W0 gemm, [10240] seed ----
// R3-proven: CSR N-trim + NT loads + analytic relu(b2) gmax seed.
__global__ __launch_bounds__(256) void k_front(const float* __restrict__ A,
                                               const float* __restrict__ x,
                                               const float* __restrict__ W0,
                                               const int* __restrict__ Nn,
                                               const float* __restrict__ b2f,
                                               float* __restrict__ gmax,
                                               unsigned short* __restrict__ adj,
                                               int* __restrict__ cnt,
                                               float* __restrict__ c1,
                                               float* __restrict__ c2,
                                               float* __restrict__ T) {
    __shared__ __align__(16) float Wl[64 * 64];    // 16 KB
    int tid = threadIdx.x;
    int wave = tid >> 6, lane = tid & 63;
    if (blockIdx.x >= 10240) {
        for (int i = tid; i < BB * 64; i += 256)
            gmax[i] = fmaxf(b2f[i & 63], 0.f);
        return;
    }
    if (blockIdx.x >= 8192) {
        int gid = blockIdx.x - 8192;        // gid%8 == b%8: XCD matches spmm
        int b = gid & 31;
        int cch = gid >> 5;
        if (cch * 16 >= Nn[b]) return;
        int row0 = (b << 10) + cch * 16;
        int rsub = lane >> 4, f0 = (lane & 15) * 4;
        int r = row0 + wave * 4 + rsub;
        const float4* xr = (const float4*)(x + (size_t)r * CIN);
        float4 acc = {0.f, 0.f, 0.f, 0.f};
#pragma unroll
        for (int kc = 0; kc < 2; ++kc) {
            if (kc) __syncthreads();
            for (int t = tid; t < 64 * 16; t += 256)
                ((float4*)Wl)[t] = ((const float4*)W0)[kc * 1024 + t];
            __syncthreads();
#pragma unroll 4
            for (int k4 = 0; k4 < 16; ++k4) {
                float4 xv = ldnt(xr + kc * 16 + k4);
                float4 w0 = *(const float4*)&Wl[(k4 * 4 + 0) * 64 + f0];
                float4 w1 = *(const float4*)&Wl[(k4 * 4 + 1) * 64 + f0];
                float4 w2 = *(const float4*)&Wl[(k4 * 4 + 2) * 64 + f0];
                float4 w3 = *(const float4*)&Wl[(k4 * 4 + 3) * 64 + f0];
                acc.x += xv.x * w0.x; acc.y += xv.x * w0.y; acc.z += xv.x * w0.z; acc.w += xv.x * w0.w;
                acc.x += xv.y * w1.x; acc.y += xv.y * w1.y; acc.z += xv.y * w1.z; acc.w += xv.y * w1.w;
                acc.x += xv.z * w2.x; acc.y += xv.z * w2.y; acc.z += xv.z * w2.z; acc.w += xv.z * w2.w;
                acc.x += xv.w * w3.x; acc.y += xv.w * w3.y; acc.z += xv.w * w3.z; acc.w += xv.w * w3.w;
            }
        }
        *(float4*)&T[(size_t)r * 64 + f0] = acc;
    } else {
        int r = blockIdx.x * 4 + wave;
        int b = r >> 10;
        int Nb = Nn[b];
        int rl = r & 1023;
        if (rl >= Nb) {
            if (lane == 0) {
                cnt[r] = 0;
                float D = 1.0f / sqrtf(1.0f + EPSV);
                c1[r] = D;
                c2[r] = D * D;
            }
            return;
        }
        unsigned short* adjs = ((unsigned short*)Wl) + wave * CAP;
        const float4* Arow = (const float4*)(A + (size_t)r * NN);
        int nch = (Nb + 255) >> 8;
        float4 z4 = {0.f, 0.f, 0.f, 0.f};
        float4 v0 = ldnt(Arow + lane);
        float4 v1 = ldnt(Arow + 64 + lane);
        float4 v2 = (nch > 2) ? ldnt(Arow + 128 + lane) : z4;
        float4 v3 = (nch > 3) ? ldnt(Arow + 192 + lane) : z4;
        int c = 0;
        unsigned long long lt = (lane == 0) ? 0ULL : ((1ULL << lane) - 1ULL);
        float4 vv[4] = {v0, v1, v2, v3};
#pragma unroll
        for (int it = 0; it < 4; ++it) {
            float4 v = vv[it];
            int j0 = it * 256 + lane * 4;
            unsigned long long m0 = __ballot(v.x != 0.f);
            unsigned long long m1 = __ballot(v.y != 0.f);
            unsigned long long m2 = __ballot(v.z != 0.f);
            unsigned long long m3 = __ballot(v.w != 0.f);
            int before = __popcll(m0 & lt) + __popcll(m1 & lt) +
                         __popcll(m2 & lt) + __popcll(m3 & lt);
            int p = c + before;
            if (v.x != 0.f) { if (p < CAP) adjs[p] = (unsigned short)(j0 + 0); ++p; }
            if (v.y != 0.f) { if (p < CAP) adjs[p] = (unsigned short)(j0 + 1); ++p; }
            if (v.z != 0.f) { if (p < CAP) adjs[p] = (unsigned short)(j0 + 2); ++p; }
            if (v.w != 0.f) { if (p < CAP) adjs[p] = (unsigned short)(j0 + 3); ++p; }
            c += __popcll(m0) + __popcll(m1) + __popcll(m2) + __popcll(m3);
        }
        int cc = (c > CAP) ? CAP : c;
        uint32_t* dst = (uint32_t*)(adj + (size_t)r * CAP);
        if (lane * 2 < cc) dst[lane] = ((const uint32_t*)adjs)[lane];
        if (lane == 0) {
            cnt[r] = cc;
            float D = 1.0f / sqrtf((float)c + 1.0f + EPSV);
            c1[r] = D;
            c2[r] = D * D;
        }
    }
}

// ---------------- fused mid: [0,8192) = deg, [8192,10240) = gemm64 (scaled) --------------
// byte-identical to R3 (proven).
__global__ __launch_bounds__(256) void k_mid(const unsigned short* __restrict__ adj,
                                             const int* __restrict__ cnt,
                                             const float* __restrict__ nm,
                                             float* __restrict__ c1, float* __restrict__ c2,
                                             const float* __restrict__ Xin,
                                             const float* __restrict__ W,
                                             const float* __restrict__ y,
                                             float* __restrict__ T,
                                             const int* __restrict__ Nn) {
    __shared__ __align__(16) float Wl[64 * 64];    // 16 KB
    int tid = threadIdx.x;
    if (blockIdx.x >= 8192) {
        int gid = blockIdx.x - 8192;
        int b = gid & 31;
        int cch = gid >> 5;
        if (cch * 16 >= Nn[b]) return;
        int row0 = (b << 10) + cch * 16;
        for (int t = tid; t < 64 * 16; t += 256)
            ((float4*)Wl)[t] = ((const float4*)W)[t];
        __syncthreads();
        int wave = tid >> 6, lane = tid & 63;
        int rsub = lane >> 4, f0 = (lane & 15) * 4;
        int r = row0 + wave * 4 + rsub;
        float sc = tanhf(y[r]) * nm[r];
        const float4* xr = (const float4*)(Xin + (size_t)r * 64);
        float4 acc = {0.f, 0.f, 0.f, 0.f};
#pragma unroll 4
        for (int k4 = 0; k4 < 16; ++k4) {
            float4 xv = ldnt(xr + k4);
            float4 w0 = *(const float4*)&Wl[(k4 * 4 + 0) * 64 + f0];
            float4 w1 = *(const float4*)&Wl[(k4 * 4 + 1) * 64 + f0];
            float4 w2 = *(const float4*)&Wl[(k4 * 4 + 2) * 64 + f0];
            float4 w3 = *(const float4*)&Wl[(k4 * 4 + 3) * 64 + f0];
            acc.x += xv.x * w0.x; acc.y += xv.x * w0.y; acc.z += xv.x * w0.z; acc.w += xv.x * w0.w;
            acc.x += xv.y * w1.x; acc.y += xv.y * w1.y; acc.z += xv.y * w1.z; acc.w += xv.y * w1.w;
            acc.x += xv.z * w2.x; acc.y += xv.z * w2.y; acc.z += xv.z * w2.z; acc.w += xv.z * w2.w;
            acc.x += xv.w * w3.x; acc.y += xv.w * w3.y; acc.z += xv.w * w3.z; acc.w += xv.w * w3.w;
        }
        acc.x *= sc; acc.y *= sc; acc.z *= sc; acc.w *= sc;
        *(float4*)&T[(size_t)r * 64 + f0] = acc;
    } else {
        int wave = tid >> 6, lane = tid & 63;
        int r = blockIdx.x * 4 + wave;
        int b = r >> 10;
        if ((r & 1023) >= Nn[b]) return;
        float m = nm[r];
        if (m == 0.f) {
            if (lane == 0) c1[r] = 0.f;
            return;
        }
        const unsigned short* arow = adj + (size_t)r * CAP;
        const float* nmb = nm + (b << 10);
        int n = cnt[r];
        float s = 0.f;
        if (lane < n)      s  = nmb[arow[lane]];
        if (lane + 64 < n) s += nmb[arow[lane + 64]];
        for (int sh = 32; sh; sh >>= 1) s += __shfl_xor(s, sh, 64);
        if (lane == 0) {
            float D = 1.0f / sqrtf(m * s + 1.0f + EPSV);
            c1[r] = m * D;
            c2[r] = D * D;
        }
    }
}

// ---------------- SpMM: 4 rows INTERLEAVED per wave (R6) ----------------
// R5 counters: 129us, 1.1% HBM, 9.5% VALU, 27% occ -> pure gather-latency-bound.
// Fix: process the wave's 4 rows concurrently. Per step: 4 index-quad loads +
// 16 independent gathers in flight (was 4), and wave duration ~ max(n_r) steps
// instead of sum. Per-row numerics unchanged: same ascending-t order, same
// acc0..acc3 split, same (acc0+acc1)+(acc2+acc3) finish.
__global__ __launch_bounds__(256) void k_spmm(const unsigned short* __restrict__ adj,
                                              const int* __restrict__ cnt,
                                              const float* __restrict__ c1,
                                              const float* __restrict__ c2,
                                              const float* __restrict__ T,
                                              const float* __restrict__ bias,
                                              float* __restrict__ X,
                                              const float* __restrict__ p,
                                              float* __restrict__ y,
                                              float* __restrict__ gmax,
                                              const int* __restrict__ Nn) {
    __shared__ __align__(16) float c1s[NN];
    __shared__ float red[4][64];
    int b   = blockIdx.x & 31;            // graph
    int cch = blockIdx.x >> 5;            // chunk in [0,64)
    int Nb = Nn[b];
    if (cch * 16 >= Nb) return;
    int tid = threadIdx.x;
    int n4 = (Nb + 3) >> 2;
    if (tid < n4) ((float4*)c1s)[tid] = ((const float4*)(c1 + (b << 10)))[tid];
    __syncthreads();
    int wave = tid >> 6, lane = tid & 63;
    int r0 = (b << 10) + cch * 16 + wave * 4;
    const float* Tb = T + ((size_t)(b << 10) << 6);
    float bv = bias[lane];
    float pv = 0.f, ppinv = 0.f;
    if (p != nullptr) {
        pv = p[lane];
        float pp = pv * pv;
        for (int s = 32; s; s >>= 1) pp += __shfl_xor(pp, s, 64);
        ppinv = 1.0f / sqrtf(pp);
    }
    // per-row state (rows live/dead wave-uniform)
    int nr[4];
    const unsigned short* ar[4];
    float a0[4], a1[4], a2[4], a3[4];
    int nmax = 0;
#pragma unroll
    for (int rr = 0; rr < 4; ++rr) {
        int r = r0 + rr;
        int rl = r & 1023;
        bool live = (rl < Nb) && (c1s[rl] != 0.f);   // layer-1 c1>0 always
        nr[rr] = live ? cnt[r] : 0;
        ar[rr] = adj + (size_t)r * CAP;
        a0[rr] = a1[rr] = a2[rr] = a3[rr] = 0.f;
        nmax = (nr[rr] > nmax) ? nr[rr] : nmax;
    }
    // interleaved quad loop: 16 gathers in flight per step
    for (int t = 0; t + 4 <= nmax; t += 4) {
#pragma unroll
        for (int rr = 0; rr < 4; ++rr) {
            if (t + 4 <= nr[rr]) {
                ushort4 j4 = *(const ushort4*)(ar[rr] + t);
                a0[rr] += c1s[j4.x] * Tb[((int)j4.x << 6) + lane];
                a1[rr] += c1s[j4.y] * Tb[((int)j4.y << 6) + lane];
                a2[rr] += c1s[j4.z] * Tb[((int)j4.z << 6) + lane];
                a3[rr] += c1s[j4.w] * Tb[((int)j4.w << 6) + lane];
            }
        }
    }
    // per-row remainder (<4 each), same order as before
#pragma unroll
    for (int rr = 0; rr < 4; ++rr) {
        for (int t = nr[rr] & ~3; t < nr[rr]; ++t) {
            int j = ar[rr][t];
            a0[rr] += c1s[j] * Tb[(j << 6) + lane];
        }
    }
    float vmax = 0.f;
#pragma unroll
    for (int rr = 0; rr < 4; ++rr) {
        int r = r0 + rr;
        int rl = r & 1023;
        if (rl >= Nb) break;
        if (c1s[rl] == 0.f) continue;
        float acc = (a0[rr] + a1[rr]) + (a2[rr] + a3[rr]);
        float o = c1s[rl] * acc + c2[r] * T[((size_t)r << 6) + lane] + bv;
        o = fmaxf(o, 0.f);
        if (X != nullptr) X[((size_t)r << 6) + lane] = o;
        if (p != nullptr) {
            float a = o * pv;
            for (int s = 32; s; s >>= 1) a += __shfl_xor(a, s, 64);
            if (lane == 0) y[r] = a * ppinv;
        }
        vmax = fmaxf(vmax, o);
    }
    if (gmax != nullptr) {
        red[wave][lane] = vmax;
        __syncthreads();
        if (wave == 0) {
            float m = fmaxf(fmaxf(red[0][lane], red[1][lane]),
                            fmaxf(red[2][lane], red[3][lane]));
            atomicMax((int*)&gmax[(b << 6) + lane], __float_as_int(m));
        }
    }
}

// ---------------- pool ranking: stable-argsort semantics, 16 blocks/graph (R3) -----------
__global__ __launch_bounds__(256) void k_rank(const float* __restrict__ y,
                                              const float* __restrict__ maskSrc,
                                              const int* __restrict__ nsrc,
                                              const int* __restrict__ nbound,
                                              float* __restrict__ nmOut,
                                              int* __restrict__ ncur) {
    __shared__ __align__(16) float yv[NN];
    int b = blockIdx.x >> 4;
    int sub = blockIdx.x & 15;
    int tid = threadIdx.x;
    const float INF = __builtin_inff();
    int Nb = nbound[b];
    if ((sub << 6) >= Nb) return;
    {
        float4 v;
        if (tid * 4 < Nb) {
            v = ((const float4*)(y + (b << 10)))[tid];
            float4 m = ((const float4*)(maskSrc + (b << 10)))[tid];
            v.x = (m.x > 0.f) ? v.x : INF;
            v.y = (m.y > 0.f) ? v.y : INF;
            v.z = (m.z > 0.f) ? v.z : INF;
            v.w = (m.w > 0.f) ? v.w : INF;
        } else {
            v.x = INF; v.y = INF; v.z = INF; v.w = INF;
        }
        ((float4*)yv)[tid] = v;
    }
    int n = nsrc[b];
    const float RM = (float)(1.0 - 0.8);
    int nrem = (int)((float)n * RM);
    if (sub == 0 && tid == 0) ncur[b] = n - nrem;
    __syncthreads();
    int i = (sub << 6) + (tid >> 2);
    int q = tid & 3;
    float yi = yv[i];
    int rank = 0;
    if (yi < INF) {
        const float4* jbase = (const float4*)yv + (q << 6);
        int j0 = q << 8;
        int tend = (Nb - j0 + 3) >> 2;
        if (tend > 64) tend = 64;
#pragma unroll 8
        for (int t = 0; t < tend; ++t) {
            float4 a = jbase[t];
            int j = j0 + t * 4;
            rank += (a.x < yi || (a.x == yi && j     < i)) ? 1 : 0;
            rank += (a.y < yi || (a.y == yi && j + 1 < i)) ? 1 : 0;
            rank += (a.z < yi || (a.z == yi && j + 2 < i)) ? 1 : 0;
            rank += (a.w < yi || (a.w == yi && j + 3 < i)) ? 1 : 0;
        }
    }
    rank += __shfl_xor(rank, 1, 64);
    rank += __shfl_xor(rank, 2, 64);
    if (q == 0) {
        float nmv = (yi < INF && rank >= nrem) ? 1.f : 0.f;
        nmOut[(b << 10) + i] = nmv;
    }
}

// ---------------- final fc from the fused global-max buffer ----------------
__global__ __launch_bounds__(64) void k_fc(const float* __restrict__ gmax,
                                           const float* __restrict__ Wfc,
                                           const float* __restrict__ bfc,
                                           float* __restrict__ out) {
    __shared__ float gl[64];
    int b = blockIdx.x, lane = threadIdx.x;
    gl[lane] = gmax[(b << 6) + lane];
    __syncthreads();
    if (lane < NOUT) {
        float acc = bfc[lane];
        for (int k = 0; k < 64; ++k) acc += gl[k] * Wfc[k * NOUT + lane];
        out[b * NOUT + lane] = acc;
    }
}

extern "C" void kernel_launch(void* const* d_in, const int* in_sizes, int n_in,
                              void* d_out, int out_size, void* d_ws, size_t ws_size,
                              hipStream_t stream) {
    const float* x    = (const float*)d_in[0];
    const float* A    = (const float*)d_in[1];
    const float* mask = (const float*)d_in[2];
    const int*   Nn   = (const int*)d_in[3];
    const float* W0   = (const float*)d_in[4];
    const float* b0   = (const float*)d_in[5];
    const float* W1   = (const float*)d_in[6];
    const float* b1   = (const float*)d_in[7];
    const float* W2   = (const float*)d_in[8];
    const float* b2   = (const float*)d_in[9];
    const float* p0   = (const float*)d_in[10];
    const float* p1   = (const float*)d_in[11];
    const float* Wfc  = (const float*)d_in[12];
    const float* bfc  = (const float*)d_in[13];
    float* out = (float*)d_out;

    char* ws = (char*)d_ws;
    size_t off = 0;
    auto alloc = [&](size_t bytes) -> void* {
        void* p = ws + off;
        off = (off + bytes + 255) & ~(size_t)255;
        return p;
    };
    unsigned short* adj = (unsigned short*)alloc((size_t)BB * NN * CAP * 2);
    int*   cnt  = (int*)  alloc((size_t)BB * NN * 4);
    float* X    = (float*)alloc((size_t)BB * NN * 64 * 4);
    float* T    = (float*)alloc((size_t)BB * NN * 64 * 4);
    float* c1   = (float*)alloc((size_t)BB * NN * 4);
    float* c2   = (float*)alloc((size_t)BB * NN * 4);
    float* y    = (float*)alloc((size_t)BB * NN * 4);
    float* nm0  = (float*)alloc((size_t)BB * NN * 4);
    float* nm1  = (float*)alloc((size_t)BB * NN * 4);
    int*   nc0  = (int*)  alloc((size_t)BB * 4);
    int*   nc1  = (int*)  alloc((size_t)BB * 4);
    float* gmax = (float*)alloc((size_t)BB * 64 * 4);

    // 1) fused: CSR (8192) + x@W0 gemm (2048) + gmax relu(b2) seed (1 block)
    k_front<<<8192 + 2048 + 1, 256, 0, stream>>>(A, x, W0, Nn, b2, gmax,
                                                 adj, cnt, c1, c2, T);
    // 2) layer-1 SpMM + pool-1 score
    k_spmm<<<2048, 256, 0, stream>>>(adj, cnt, c1, c2, T, b0, X, p0, y, nullptr, Nn);
    // pool 1
    k_rank<<<BB * 16, 256, 0, stream>>>(y, mask, Nn, Nn, nm0, nc0);
    // 3) layer 2: fused deg (first) + gemm64
    k_mid<<<8192 + 2048, 256, 0, stream>>>(adj, cnt, nm0, c1, c2, X, W1, y, T, Nn);
    k_spmm<<<2048, 256, 0, stream>>>(adj, cnt, c1, c2, T, b1, X, p1, y, nullptr, Nn);
    // pool 2
    k_rank<<<BB * 16, 256, 0, stream>>>(y, nm0, nc0, Nn, nm1, nc1);
    // 4) layer 3: fused deg (first) + gemm64; spmm fuses global max (no X write)
    k_mid<<<8192 + 2048, 256, 0, stream>>>(adj, cnt, nm1, c1, c2, X, W2, y, T, Nn);
    k_spmm<<<2048, 256, 0, stream>>>(adj, cnt, c1, c2, T, b2, nullptr, nullptr, nullptr,
                                     gmax, Nn);
    // 5) fc from gmax
    k_fc<<<BB, 64, 0, stream>>>(gmax, Wfc, bfc, out);
}